// Round 1
// baseline (449.169 us; speedup 1.0000x reference)
//
#include <hip/hip_runtime.h>

// GAT layer as flash-attention: Q = h*a3, K = V = h, biases s_self/s_nei,
// leakyrelu(0.2) + adj mask + online softmax + PV, final ELU.
// Phase 2 is HBM-bound on the 268 MB adj stream (floor ~43 us).

typedef __attribute__((ext_vector_type(8))) short bf16x8;
typedef __attribute__((ext_vector_type(4))) float f32x4;

#define NEG_INF_F (-__builtin_huge_valf())
#define NEG_BIG   (-9000000000000000.0f)

__device__ __forceinline__ unsigned short f2bf(float f) {
  unsigned int u = __float_as_uint(f);
  u += 0x7fffu + ((u >> 16) & 1u);   // RNE
  return (unsigned short)(u >> 16);
}

// ---------------- phase 1: h = x@W (fp32), biases, bf16 packs ----------------
// 512 blocks x 256 thr; block = 32 rows x 64 f; thread tile = 2 rows x 4 f.
__global__ __launch_bounds__(256) void gat_phase1(
    const float* __restrict__ x,        // [4][4096][128]
    const float* __restrict__ W,        // [128][64]
    const float* __restrict__ a,        // [192]
    unsigned short* __restrict__ h_bf,  // [4][4096][64]
    unsigned short* __restrict__ hT_bf, // [4][64][4096]
    unsigned short* __restrict__ q_bf,  // [4][4096][64]
    float* __restrict__ s_self,         // [4][4096]
    float* __restrict__ s_nei)          // [4][4096]
{
  __shared__ float xs[32 * 132];  // x tile, stride 132 (pad 4) for bank spread
  __shared__ float wt[64 * 132];  // W^T [f][k]
  const int tid = threadIdx.x;
  const int bx  = blockIdx.x;
  const int b   = bx >> 7;
  const int n0  = (bx & 127) << 5;
  const float* xb = x + ((size_t)b * 4096 + n0) * 128;

#pragma unroll
  for (int p = 0; p < 4; ++p) {
    int idx = tid + p * 256;
    int row = idx >> 5, c4 = idx & 31;
    float4 v = ((const float4*)(xb + row * 128))[c4];
    *(float4*)&xs[row * 132 + c4 * 4] = v;
  }
#pragma unroll
  for (int p = 0; p < 8; ++p) {
    int idx = tid + p * 256;
    int k = idx >> 4, f4 = idx & 15;
    float4 v = ((const float4*)(W + k * 64))[f4];
    wt[(f4 * 4 + 0) * 132 + k] = v.x;
    wt[(f4 * 4 + 1) * 132 + k] = v.y;
    wt[(f4 * 4 + 2) * 132 + k] = v.z;
    wt[(f4 * 4 + 3) * 132 + k] = v.w;
  }
  __syncthreads();

  const int tx = tid & 15;   // f = 4*tx + fi
  const int ty = tid >> 4;   // n = n0 + 2*ty + ri
  float acc[2][4];
#pragma unroll
  for (int r = 0; r < 2; ++r)
#pragma unroll
    for (int f = 0; f < 4; ++f) acc[r][f] = 0.f;

#pragma unroll 4
  for (int k = 0; k < 128; k += 4) {
    float4 xv[2], wv[4];
#pragma unroll
    for (int r = 0; r < 2; ++r) xv[r] = *(const float4*)&xs[(2 * ty + r) * 132 + k];
#pragma unroll
    for (int f = 0; f < 4; ++f) wv[f] = *(const float4*)&wt[(4 * tx + f) * 132 + k];
#pragma unroll
    for (int r = 0; r < 2; ++r)
#pragma unroll
      for (int f = 0; f < 4; ++f)
        acc[r][f] += xv[r].x * wv[f].x + xv[r].y * wv[f].y +
                     xv[r].z * wv[f].z + xv[r].w * wv[f].w;
  }

  float a1r[4], a2r[4], a3r[4];
#pragma unroll
  for (int f = 0; f < 4; ++f) {
    a1r[f] = a[4 * tx + f];
    a2r[f] = a[64 + 4 * tx + f];
    a3r[f] = a[128 + 4 * tx + f];
  }
  const size_t bN = (size_t)b * 4096;
  // s_self / s_nei: reduce over f -> 16-lane shfl groups (lane = (ty&3)*16+tx)
#pragma unroll
  for (int r = 0; r < 2; ++r) {
    float p1 = 0.f, p2 = 0.f;
#pragma unroll
    for (int f = 0; f < 4; ++f) { p1 += acc[r][f] * a1r[f]; p2 += acc[r][f] * a2r[f]; }
#pragma unroll
    for (int m = 1; m < 16; m <<= 1) {
      p1 += __shfl_xor(p1, m, 64);
      p2 += __shfl_xor(p2, m, 64);
    }
    if (tx == 0) {
      int n = n0 + 2 * ty + r;
      s_self[bN + n] = p1;
      s_nei[bN + n]  = p2;
    }
  }
#pragma unroll
  for (int r = 0; r < 2; ++r) {
    int n = n0 + 2 * ty + r;
    ushort4 hv, qv;
    hv.x = f2bf(acc[r][0]); hv.y = f2bf(acc[r][1]);
    hv.z = f2bf(acc[r][2]); hv.w = f2bf(acc[r][3]);
    qv.x = f2bf(acc[r][0] * a3r[0]); qv.y = f2bf(acc[r][1] * a3r[1]);
    qv.z = f2bf(acc[r][2] * a3r[2]); qv.w = f2bf(acc[r][3] * a3r[3]);
    *(ushort4*)&h_bf[(bN + n) * 64 + 4 * tx] = hv;
    *(ushort4*)&q_bf[(bN + n) * 64 + 4 * tx] = qv;
  }
#pragma unroll
  for (int f = 0; f < 4; ++f) {      // transposed copy for PV B-operand
    ushort2 tv;
    tv.x = f2bf(acc[0][f]);
    tv.y = f2bf(acc[1][f]);
    *(ushort2*)&hT_bf[((size_t)b * 64 + 4 * tx + f) * 4096 + n0 + 2 * ty] = tv;
  }
}

// ---------------- phase 2: flash-attention over adj ----------------
// 256 blocks (1/CU) x 256 thr (4 waves x 16 rows). j-tiles of 64.
// MFMA 16x16x32 bf16 layouts (m89/m74-verified):
//   A: lane holds A[m=lane&15][k=(lane>>4)*8 + j]
//   B: lane holds B[k=(lane>>4)*8 + j][n=lane&15]
//   C/D: lane holds D[row=(lane>>4)*4 + reg][col=lane&15]
__global__ __launch_bounds__(256) void gat_phase2(
    const unsigned short* __restrict__ h_bf,
    const unsigned short* __restrict__ hT_bf,
    const unsigned short* __restrict__ q_bf,
    const float* __restrict__ s_self,
    const float* __restrict__ s_nei,
    const int* __restrict__ adj,
    float* __restrict__ out)
{
  __shared__ unsigned short Kbuf[64 * 72];      // K rows [j][f], pad 72
  __shared__ unsigned short Tbuf[64 * 72];      // V^T rows [f][j], pad 72
  __shared__ unsigned short Pbuf[4][16 * 72];   // per-wave P round-trip

  const int tid = threadIdx.x;
  const int w = tid >> 6, lane = tid & 63;
  const int qd = lane >> 4, c = lane & 15;
  const int bx = blockIdx.x;
  const int b = bx & 3;                 // XCD->batch affinity (L2 locality)
  const int i0 = ((bx >> 2) << 6) + (w << 4);
  const size_t bN = (size_t)b * 4096;

  // Q fragments (A-operand), K split in two 32-chunks
  bf16x8 Qf0 = *(const bf16x8*)(q_bf + (bN + i0 + c) * 64 + qd * 8);
  bf16x8 Qf1 = *(const bf16x8*)(q_bf + (bN + i0 + c) * 64 + 32 + qd * 8);

  float ss[4];
  const int* adjp[4];
#pragma unroll
  for (int r = 0; r < 4; ++r) {
    ss[r] = s_self[bN + i0 + 4 * qd + r];
    adjp[r] = adj + (bN + i0 + 4 * qd + r) * 4096;
  }

  float m_i[4], l_i[4];
  f32x4 O[4];
#pragma unroll
  for (int r = 0; r < 4; ++r) { m_i[r] = NEG_INF_F; l_i[r] = 0.f; }
#pragma unroll
  for (int ct = 0; ct < 4; ++ct) O[ct] = (f32x4){0.f, 0.f, 0.f, 0.f};

  for (int jt = 0; jt < 4096; jt += 64) {
    // ---- stage K and V^T tiles into LDS (coalesced uint4) ----
#pragma unroll
    for (int p = 0; p < 2; ++p) {
      int idx = tid + p * 256;
      int row = idx >> 3, c8 = (idx & 7) * 8;
      uint4 kv = *(const uint4*)(h_bf + (bN + jt + row) * 64 + c8);
      *(uint4*)&Kbuf[row * 72 + c8] = kv;
      uint4 tv = *(const uint4*)(hT_bf + ((size_t)b * 64 + row) * 4096 + jt + c8);
      *(uint4*)&Tbuf[row * 72 + c8] = tv;
    }
    __syncthreads();

    // adj stream: 16 coalesced dwords/lane -- the HBM-bound part; issue early
    int adjv[4][4];
#pragma unroll
    for (int ct = 0; ct < 4; ++ct)
#pragma unroll
      for (int r = 0; r < 4; ++r)
        adjv[ct][r] = adjp[r][jt + 16 * ct + c];
    float sn[4];
#pragma unroll
    for (int ct = 0; ct < 4; ++ct) sn[ct] = s_nei[bN + jt + 16 * ct + c];

    // ---- S = Q K^T ----
    f32x4 S[4];
#pragma unroll
    for (int ct = 0; ct < 4; ++ct) {
      bf16x8 Kf0 = *(const bf16x8*)&Kbuf[(16 * ct + c) * 72 + qd * 8];
      bf16x8 Kf1 = *(const bf16x8*)&Kbuf[(16 * ct + c) * 72 + 32 + qd * 8];
      f32x4 acc = (f32x4){0.f, 0.f, 0.f, 0.f};
      acc = __builtin_amdgcn_mfma_f32_16x16x32_bf16(Qf0, Kf0, acc, 0, 0, 0);
      acc = __builtin_amdgcn_mfma_f32_16x16x32_bf16(Qf1, Kf1, acc, 0, 0, 0);
      S[ct] = acc;
    }

    // ---- bias + leakyrelu + mask + online softmax (per row 4*qd+r) ----
#pragma unroll
    for (int r = 0; r < 4; ++r) {
      float ev[4];
      float mx = NEG_INF_F;
#pragma unroll
      for (int ct = 0; ct < 4; ++ct) {
        float e = S[ct][r] + ss[r] + sn[ct];
        e = e > 0.f ? e : 0.2f * e;
        e = adjv[ct][r] > 0 ? e : NEG_BIG;
        ev[ct] = e;
        mx = fmaxf(mx, e);
      }
#pragma unroll
      for (int m = 1; m < 16; m <<= 1) mx = fmaxf(mx, __shfl_xor(mx, m, 64));
      float mn = fmaxf(m_i[r], mx);
      float alpha = __expf(m_i[r] - mn);   // first tile: exp(-inf)=0
      m_i[r] = mn;
      float rsum = 0.f;
#pragma unroll
      for (int ct = 0; ct < 4; ++ct) {
        float p = __expf(ev[ct] - mn);
        rsum += p;
        Pbuf[w][(4 * qd + r) * 72 + 16 * ct + c] = f2bf(p);
      }
#pragma unroll
      for (int m = 1; m < 16; m <<= 1) rsum += __shfl_xor(rsum, m, 64);
      l_i[r] = l_i[r] * alpha + rsum;
#pragma unroll
      for (int ct = 0; ct < 4; ++ct) O[ct][r] *= alpha;
    }
    __syncthreads();   // Pbuf C-layout -> A-layout round trip (cross-lane RAW)

    // ---- O += P V ----
#pragma unroll
    for (int kc = 0; kc < 2; ++kc) {
      bf16x8 Pf = *(const bf16x8*)&Pbuf[w][c * 72 + kc * 32 + qd * 8];
#pragma unroll
      for (int ct = 0; ct < 4; ++ct) {
        bf16x8 Vf = *(const bf16x8*)&Tbuf[(16 * ct + c) * 72 + kc * 32 + qd * 8];
        O[ct] = __builtin_amdgcn_mfma_f32_16x16x32_bf16(Pf, Vf, O[ct], 0, 0, 0);
      }
    }
    __syncthreads();   // protect Kbuf/Tbuf before next stage
  }

  // ---- epilogue: normalize + ELU ----
#pragma unroll
  for (int r = 0; r < 4; ++r) {
    float invl = 1.0f / l_i[r];
#pragma unroll
    for (int ct = 0; ct < 4; ++ct) {
      float v = O[ct][r] * invl;
      v = v > 0.f ? v : __expf(v) - 1.0f;
      out[(bN + i0 + 4 * qd + r) * 64 + 16 * ct + c] = v;
    }
  }
}

extern "C" void kernel_launch(void* const* d_in, const int* in_sizes, int n_in,
                              void* d_out, int out_size, void* d_ws, size_t ws_size,
                              hipStream_t stream) {
  const float* x  = (const float*)d_in[0];
  const int* adj  = (const int*)d_in[1];
  const float* W  = (const float*)d_in[2];
  const float* a  = (const float*)d_in[3];
  float* out = (float*)d_out;

  char* ws = (char*)d_ws;
  unsigned short* h_bf  = (unsigned short*)(ws);                 // 2 MB
  unsigned short* hT_bf = (unsigned short*)(ws + (2u << 20));    // 2 MB
  unsigned short* q_bf  = (unsigned short*)(ws + (4u << 20));    // 2 MB
  float* s_self = (float*)(ws + (6u << 20));                     // 64 KB
  float* s_nei  = (float*)(ws + (6u << 20) + (64u << 10));       // 64 KB

  gat_phase1<<<512, 256, 0, stream>>>(x, W, a, h_bf, hT_bf, q_bf, s_self, s_nei);
  gat_phase2<<<256, 256, 0, stream>>>(h_bf, hT_bf, q_bf, s_self, s_nei, adj, out);
}

// Round 3
// 409.777 us; speedup vs baseline: 1.0961x; 1.0961x over previous
//
#include <hip/hip_runtime.h>

// GAT as flash-attention, restructured for occupancy:
//  - fixed-scale softmax: p = exp2(leaky(e)*log2e), global scale cancels in O/l
//    -> no running max, no rescale, no reductions in the j-loop
//  - S^T formulation: mfma(K,Q) puts P directly into the B-operand layout of
//    the 16x16x16 PV MFMA (O^T = V^T P^T): no P LDS round-trip, 1 fewer barrier
//  - j-split x4 (flash-decoding) -> 1024 blocks -> 16 waves/CU; combine kernel
//  - fp16 pipeline (h, hT, q), uint4 adj loads, pipelined staging + adj prefetch

typedef __attribute__((ext_vector_type(4))) float f32x4;
typedef __attribute__((ext_vector_type(4))) _Float16 h16x4;
typedef __attribute__((ext_vector_type(8))) _Float16 h16x8;
typedef __attribute__((ext_vector_type(2))) __fp16 fp16x2;

#define L2E 1.4426950408889634f

// ---------------- phase 1: h = x@W (fp32), scaled biases, fp16 packs --------
// 512 blocks x 256 thr; block = 32 rows x 64 f; thread tile = 2 rows x 4 f.
__global__ __launch_bounds__(256) void gat_phase1(
    const float* __restrict__ x,        // [4][4096][128]
    const float* __restrict__ W,        // [128][64]
    const float* __restrict__ a,        // [192]
    _Float16* __restrict__ h16,         // [4][4096][64]
    _Float16* __restrict__ hT16,        // [4][64][4096]
    _Float16* __restrict__ q16,         // [4][4096][64]  (pre-scaled by log2e)
    float* __restrict__ sS,             // [4][4096]      (pre-scaled by log2e)
    float* __restrict__ sN)             // [4][4096]      (pre-scaled by log2e)
{
  __shared__ float xs[32 * 132];
  __shared__ float wt[64 * 132];
  const int tid = threadIdx.x;
  const int bx  = blockIdx.x;
  const int b   = bx >> 7;
  const int n0  = (bx & 127) << 5;
  const float* xb = x + ((size_t)b * 4096 + n0) * 128;

#pragma unroll
  for (int p = 0; p < 4; ++p) {
    int idx = tid + p * 256;
    int row = idx >> 5, c4 = idx & 31;
    float4 v = ((const float4*)(xb + row * 128))[c4];
    *(float4*)&xs[row * 132 + c4 * 4] = v;
  }
#pragma unroll
  for (int p = 0; p < 8; ++p) {
    int idx = tid + p * 256;
    int k = idx >> 4, f4 = idx & 15;
    float4 v = ((const float4*)(W + k * 64))[f4];
    wt[(f4 * 4 + 0) * 132 + k] = v.x;
    wt[(f4 * 4 + 1) * 132 + k] = v.y;
    wt[(f4 * 4 + 2) * 132 + k] = v.z;
    wt[(f4 * 4 + 3) * 132 + k] = v.w;
  }
  __syncthreads();

  const int tx = tid & 15;   // f = 4*tx + fi
  const int ty = tid >> 4;   // n = n0 + 2*ty + ri
  float acc[2][4];
#pragma unroll
  for (int r = 0; r < 2; ++r)
#pragma unroll
    for (int f = 0; f < 4; ++f) acc[r][f] = 0.f;

#pragma unroll 4
  for (int k = 0; k < 128; k += 4) {
    float4 xv[2], wv[4];
#pragma unroll
    for (int r = 0; r < 2; ++r) xv[r] = *(const float4*)&xs[(2 * ty + r) * 132 + k];
#pragma unroll
    for (int f = 0; f < 4; ++f) wv[f] = *(const float4*)&wt[(4 * tx + f) * 132 + k];
#pragma unroll
    for (int r = 0; r < 2; ++r)
#pragma unroll
      for (int f = 0; f < 4; ++f)
        acc[r][f] += xv[r].x * wv[f].x + xv[r].y * wv[f].y +
                     xv[r].z * wv[f].z + xv[r].w * wv[f].w;
  }

  float a1r[4], a2r[4], a3r[4];
#pragma unroll
  for (int f = 0; f < 4; ++f) {
    a1r[f] = a[4 * tx + f] * L2E;
    a2r[f] = a[64 + 4 * tx + f] * L2E;
    a3r[f] = a[128 + 4 * tx + f] * L2E;
  }
  const size_t bN = (size_t)b * 4096;
#pragma unroll
  for (int r = 0; r < 2; ++r) {
    float p1 = 0.f, p2 = 0.f;
#pragma unroll
    for (int f = 0; f < 4; ++f) { p1 += acc[r][f] * a1r[f]; p2 += acc[r][f] * a2r[f]; }
#pragma unroll
    for (int m = 1; m < 16; m <<= 1) {
      p1 += __shfl_xor(p1, m, 64);
      p2 += __shfl_xor(p2, m, 64);
    }
    if (tx == 0) {
      int n = n0 + 2 * ty + r;
      sS[bN + n] = p1;
      sN[bN + n] = p2;
    }
  }
#pragma unroll
  for (int r = 0; r < 2; ++r) {
    int n = n0 + 2 * ty + r;
    h16x4 hv, qv;
#pragma unroll
    for (int f = 0; f < 4; ++f) {
      hv[f] = (_Float16)acc[r][f];
      qv[f] = (_Float16)(acc[r][f] * a3r[f]);
    }
    *(h16x4*)&h16[(bN + n) * 64 + 4 * tx] = hv;
    *(h16x4*)&q16[(bN + n) * 64 + 4 * tx] = qv;
  }
  __syncthreads();                       // xs reads done; reuse as hT staging
  _Float16* hTs = (_Float16*)xs;         // [64][40] halves (5.1 KB)
#pragma unroll
  for (int f = 0; f < 4; ++f)
#pragma unroll
    for (int r = 0; r < 2; ++r)
      hTs[(4 * tx + f) * 40 + 2 * ty + r] = (_Float16)acc[r][f];
  __syncthreads();
  {
    int f = tid >> 2, part = tid & 3;    // 16B per thread, 64B per f-row
    uint4 v = *(uint4*)&hTs[f * 40 + 8 * part];
    *(uint4*)&hT16[((size_t)b * 64 + f) * 4096 + n0 + 8 * part] = v;
  }
}

// ---------------- phase 2: masked softmax-attention partials ----------------
// 1024 blocks (b,split,itile) x 256 thr (4 waves x 16 rows). j-quarter = 1024.
// MFMA layouts: 16x16x32 A[m=lane&15][k=qd*8+j], B[k=qd*8+j][n=lane&15],
//               16x16x16 A[m=lane&15][k=qd*4+j], B[k=qd*4+j][n=lane&15],
//               C/D row=(lane>>4)*4+reg, col=lane&15.
__global__ __launch_bounds__(256, 4) void gat_phase2(
    const _Float16* __restrict__ h16,
    const _Float16* __restrict__ hT16,
    const _Float16* __restrict__ q16,
    const float* __restrict__ sS,
    const float* __restrict__ sN,
    const int* __restrict__ adj,
    float* __restrict__ Opart,          // [4][16384][64]
    float* __restrict__ lpart)          // [4][16384]
{
  __shared__ _Float16 Kbuf[64 * 72];    // K rows [j][f], stride 72 (16B align)
  __shared__ _Float16 Tbuf[64 * 72];    // V^T rows [f][j]

  const int tid = threadIdx.x;
  const int w = tid >> 6, lane = tid & 63;
  const int qd = lane >> 4, c = lane & 15;
  const int bx = blockIdx.x;
  const int b = bx & 3;
  const int split = (bx >> 2) & 3;
  const int it = bx >> 4;
  const int i0 = it * 64 + w * 16;
  const int jq0 = split * 1024;
  const size_t bN = (size_t)b * 4096;

  // Q fragment: B-operand of S^T (Q^T[f][i]), lane holds Q[i=c][f-slice]
  const _Float16* qrow = q16 + (bN + i0 + c) * 64;
  h16x8 Qf0 = *(const h16x8*)(qrow + qd * 8);
  h16x8 Qf1 = *(const h16x8*)(qrow + 32 + qd * 8);
  const float ss = sS[bN + i0 + c];

  const int* adjb = adj + (bN + i0 + c) * 4096 + jq0 + 4 * qd;
  const float* snb = sN + bN + jq0 + 4 * qd;

  // staging addressing
  const int srow = tid >> 3, sc8 = (tid & 7) * 8;
  const _Float16* hsrc = h16 + (bN + jq0 + srow) * 64 + sc8;        // +32 rows pass 2
  const _Float16* tsrc = hT16 + ((size_t)b * 64 + srow) * 4096 + jq0 + sc8;

  f32x4 O[4];
#pragma unroll
  for (int ft = 0; ft < 4; ++ft) O[ft] = (f32x4){0.f, 0.f, 0.f, 0.f};
  float lsum = 0.f;

  // prefetch tile 0: staging regs + adj
  uint4 kr0 = *(const uint4*)hsrc, kr1 = *(const uint4*)(hsrc + 32 * 64);
  uint4 tr0 = *(const uint4*)tsrc, tr1 = *(const uint4*)(tsrc + 32 * 4096);
  uint4 av[4];
#pragma unroll
  for (int ct = 0; ct < 4; ++ct) av[ct] = *(const uint4*)(adjb + 16 * ct);

  for (int t = 0; t < 16; ++t) {
    const int joff = t * 64;
    __syncthreads();                    // prev readers done; LDS writable
    *(uint4*)&Kbuf[srow * 72 + sc8] = kr0;
    *(uint4*)&Kbuf[(srow + 32) * 72 + sc8] = kr1;
    *(uint4*)&Tbuf[srow * 72 + sc8] = tr0;
    *(uint4*)&Tbuf[(srow + 32) * 72 + sc8] = tr1;
    __syncthreads();                    // tiles visible

    uint4 avn[4] = {av[0], av[1], av[2], av[3]};
    if (t < 15) {                       // prefetch next tile during compute
      const _Float16* hs = hsrc + (joff + 64) * 64;
      const _Float16* ts = tsrc + (joff + 64);
      kr0 = *(const uint4*)hs; kr1 = *(const uint4*)(hs + 32 * 64);
      tr0 = *(const uint4*)ts; tr1 = *(const uint4*)(ts + 32 * 4096);
#pragma unroll
      for (int ct = 0; ct < 4; ++ct)
        avn[ct] = *(const uint4*)(adjb + joff + 64 + 16 * ct);
    }

#pragma unroll
    for (int ct = 0; ct < 4; ++ct) {
      // S^T chunk: rows j=16ct+4qd+r, col i=c
      h16x8 Kf0 = *(const h16x8*)&Kbuf[(16 * ct + c) * 72 + qd * 8];
      h16x8 Kf1 = *(const h16x8*)&Kbuf[(16 * ct + c) * 72 + 32 + qd * 8];
      f32x4 Sv = (f32x4){0.f, 0.f, 0.f, 0.f};
      Sv = __builtin_amdgcn_mfma_f32_16x16x32_f16(Kf0, Qf0, Sv, 0, 0, 0);
      Sv = __builtin_amdgcn_mfma_f32_16x16x32_f16(Kf1, Qf1, Sv, 0, 0, 0);

      f32x4 snv = *(const f32x4*)(snb + joff + 16 * ct);
      f32x4 ev = Sv + snv + ss;                    // e * log2e
      f32x4 tv = __builtin_elementwise_max(ev, ev * 0.2f);  // leakyrelu
      float p0 = __builtin_amdgcn_exp2f(tv.x);
      float p1 = __builtin_amdgcn_exp2f(tv.y);
      float p2 = __builtin_amdgcn_exp2f(tv.z);
      float p3 = __builtin_amdgcn_exp2f(tv.w);
      p0 = av[ct].x ? p0 : 0.f;
      p1 = av[ct].y ? p1 : 0.f;
      p2 = av[ct].z ? p2 : 0.f;
      p3 = av[ct].w ? p3 : 0.f;
      lsum += (p0 + p1) + (p2 + p3);
      fp16x2 plo = __builtin_amdgcn_cvt_pkrtz(p0, p1);
      fp16x2 phi = __builtin_amdgcn_cvt_pkrtz(p2, p3);
      h16x4 Pf = (h16x4){(_Float16)plo.x, (_Float16)plo.y,
                         (_Float16)phi.x, (_Float16)phi.y};  // B-op: P^T[j][i=c]

      // O^T[f][i] += V^T[f][j] * P^T[j][i]
#pragma unroll
      for (int ft = 0; ft < 4; ++ft) {
        h16x4 Vf = *(const h16x4*)&Tbuf[(16 * ft + c) * 72 + 16 * ct + 4 * qd];
        O[ft] = __builtin_amdgcn_mfma_f32_16x16x16f16(Vf, Pf, O[ft], 0, 0, 0);
      }
    }
#pragma unroll
    for (int ct = 0; ct < 4; ++ct) av[ct] = avn[ct];
  }

  // l: sum over qd groups (full j-quarter per row i=c)
  lsum += __shfl_xor(lsum, 16, 64);
  lsum += __shfl_xor(lsum, 32, 64);

  // lane c owns output row i0+c: O^T col=c, rows f=16ft+4qd+r (contig in r)
  float* orow = Opart + ((size_t)split * 16384 + bN + i0 + c) * 64;
#pragma unroll
  for (int ft = 0; ft < 4; ++ft)
    *(f32x4*)(orow + 16 * ft + 4 * qd) = O[ft];
  if (lane < 16) lpart[split * 16384 + bN + i0 + c] = lsum;
}

// ---------------- phase 3: combine splits + normalize + ELU ----------------
__global__ __launch_bounds__(256) void gat_combine(
    const float* __restrict__ Opart, const float* __restrict__ lpart,
    float* __restrict__ out)
{
  const int tid = threadIdx.x;
  const size_t row = (size_t)blockIdx.x * 16 + (tid >> 4);
  const int f4 = (tid & 15) * 4;
  const size_t R = 16384;
  float l = lpart[row] + lpart[R + row] + lpart[2 * R + row] + lpart[3 * R + row];
  f32x4 o = *(const f32x4*)&Opart[row * 64 + f4];
  o += *(const f32x4*)&Opart[(R + row) * 64 + f4];
  o += *(const f32x4*)&Opart[(2 * R + row) * 64 + f4];
  o += *(const f32x4*)&Opart[(3 * R + row) * 64 + f4];
  float inv = 1.0f / l;
  float4 res;
  float v;
  v = o.x * inv; res.x = v > 0.f ? v : __expf(v) - 1.f;
  v = o.y * inv; res.y = v > 0.f ? v : __expf(v) - 1.f;
  v = o.z * inv; res.z = v > 0.f ? v : __expf(v) - 1.f;
  v = o.w * inv; res.w = v > 0.f ? v : __expf(v) - 1.f;
  *(float4*)&out[row * 64 + f4] = res;
}

extern "C" void kernel_launch(void* const* d_in, const int* in_sizes, int n_in,
                              void* d_out, int out_size, void* d_ws, size_t ws_size,
                              hipStream_t stream) {
  const float* x  = (const float*)d_in[0];
  const int* adj  = (const int*)d_in[1];
  const float* W  = (const float*)d_in[2];
  const float* a  = (const float*)d_in[3];
  float* out = (float*)d_out;

  char* ws = (char*)d_ws;
  _Float16* h16  = (_Float16*)(ws);                      // 2 MB
  _Float16* hT16 = (_Float16*)(ws + (2u << 20));         // 2 MB
  _Float16* q16  = (_Float16*)(ws + (4u << 20));         // 2 MB
  float* sS = (float*)(ws + (6u << 20));                 // 64 KB
  float* sN = (float*)(ws + (6u << 20) + (64u << 10));   // 64 KB
  float* Opart = (float*)(ws + (6u << 20) + (128u << 10));          // 16.78 MB
  float* lpart = (float*)(ws + (6u << 20) + (128u << 10) + (16u << 20)); // 256 KB

  gat_phase1<<<512, 256, 0, stream>>>(x, W, a, h16, hT16, q16, sS, sN);
  gat_phase2<<<1024, 256, 0, stream>>>(h16, hT16, q16, sS, sN, adj, Opart, lpart);
  gat_combine<<<1024, 256, 0, stream>>>(Opart, lpart, out);
}